// Round 1
// baseline (471.114 us; speedup 1.0000x reference)
//
#include <hip/hip_runtime.h>

#define E_CNT 200000
#define N_CNT 50000

typedef __attribute__((ext_vector_type(8))) unsigned short ushort8;
typedef __attribute__((ext_vector_type(4))) float f32x4;
typedef __bf16 bf16x8 __attribute__((ext_vector_type(8)));

static __device__ __forceinline__ unsigned short f2bf(float f) {
  unsigned int u = __builtin_bit_cast(unsigned int, f);
  u += 0x7FFFu + ((u >> 16) & 1u);
  return (unsigned short)(u >> 16);
}

// W [K][256] f32 (row-major) -> frag-ready bf16: Bp[(kc*16 + F)*64 + lane][8]
// lane holds B[kc*32 + (lane>>4)*8 + j][F*16 + (lane&15)], j=0..7
__global__ void prep_w(const float* __restrict__ W, unsigned short* __restrict__ Bp, int KC) {
  int idx = blockIdx.x * blockDim.x + threadIdx.x;
  int total = KC * 16 * 64;
  if (idx >= total) return;
  int lane = idx & 63;
  int t = idx >> 6;
  int F = t & 15;
  int kc = t >> 4;
  int col = F * 16 + (lane & 15);
  int kb = kc * 32 + (lane >> 4) * 8;
  ushort8 v;
#pragma unroll
  for (int j = 0; j < 8; ++j) v[j] = f2bf(W[(size_t)(kb + j) * 256 + col]);
  *reinterpret_cast<ushort8*>(Bp + (size_t)idx * 8) = v;
}

// Tiled MFMA GEMM: out[M,256] = relu(concat-input @ W + bias)
// EDGE: input row e = [edges[e] | nodes[senders[e]] | nodes[receivers[e]] | globals] (K=896)
//       + atomicAdd rows into agg[receivers[e]]
// NODE: input row n = [agg[n] | nodes[n] | globals] (K=640)
template <int NSTEPS, bool EDGE>
__global__ __launch_bounds__(512) void gemm_mlp(
    const float* __restrict__ in0, const float* __restrict__ nodes,
    const float* __restrict__ gl, const int* __restrict__ senders,
    const int* __restrict__ receivers, const unsigned short* __restrict__ Bp,
    const float* __restrict__ bias, float* __restrict__ out,
    float* __restrict__ agg, int M) {
  __shared__ unsigned short lds[128 * 64];  // A tile: 128 rows x 64 k, bf16, 16B-slot swizzled

  const int tid = threadIdx.x;
  const int lane = tid & 63;
  const int wave = tid >> 6;  // 0..7
  const int wm = wave >> 2;   // 0..1 : 64-row half
  const int wn = wave & 3;    // 0..3 : 64-col quarter
  const int row0 = blockIdx.x * 128;

  // staging: thread stages 16 consecutive floats of one row per K-step
  const int sr = tid >> 2;  // 0..127 row within tile
  const int sc = tid & 3;   // which 16-float chunk
  int er = row0 + sr;
  if (er > M - 1) er = M - 1;

  const float* bases[4];
  if (EDGE) {
    int si = senders[er], ri = receivers[er];
    bases[0] = in0 + (size_t)er * 256;
    bases[1] = nodes + (size_t)si * 256;
    bases[2] = nodes + (size_t)ri * 256;
    bases[3] = gl;
  } else {
    bases[0] = in0 + (size_t)er * 256;
    bases[1] = nodes + (size_t)er * 256;
    bases[2] = gl;
    bases[3] = gl;
  }

  const int swz = sr & 7;
  const int wbase = sr * 64;

  f32x4 acc[4][4] = {};

#pragma unroll
  for (int ks = 0; ks < NSTEPS; ++ks) {
    // ---- stage A tile (fp32 -> bf16 -> LDS, swizzled) ----
    const float* srcp = bases[ks >> 2] + (ks & 3) * 64 + sc * 16;
    const float4* p4 = reinterpret_cast<const float4*>(srcp);
    float fv[16];
    *reinterpret_cast<float4*>(&fv[0]) = p4[0];
    *reinterpret_cast<float4*>(&fv[4]) = p4[1];
    *reinterpret_cast<float4*>(&fv[8]) = p4[2];
    *reinterpret_cast<float4*>(&fv[12]) = p4[3];
    ushort8 w0, w1;
#pragma unroll
    for (int j = 0; j < 8; ++j) {
      w0[j] = f2bf(fv[j]);
      w1[j] = f2bf(fv[8 + j]);
    }
    int s0 = (sc * 2) ^ swz;
    int s1 = (sc * 2 + 1) ^ swz;
    *reinterpret_cast<ushort8*>(&lds[wbase + s0 * 8]) = w0;
    *reinterpret_cast<ushort8*>(&lds[wbase + s1 * 8]) = w1;
    __syncthreads();

    // ---- MFMA ----
#pragma unroll
    for (int kk = 0; kk < 2; ++kk) {
      bf16x8 a[4];
#pragma unroll
      for (int fm = 0; fm < 4; ++fm) {
        int r = wm * 64 + fm * 16 + (lane & 15);
        int slot = (kk * 4 + (lane >> 4)) ^ (r & 7);
        a[fm] = __builtin_bit_cast(
            bf16x8, *reinterpret_cast<const ushort8*>(&lds[r * 64 + slot * 8]));
      }
      bf16x8 b[4];
      const int kc32 = ks * 2 + kk;
#pragma unroll
      for (int fn = 0; fn < 4; ++fn) {
        int F = wn * 4 + fn;
        b[fn] = __builtin_bit_cast(
            bf16x8, *reinterpret_cast<const ushort8*>(
                        Bp + ((size_t)(kc32 * 16 + F) * 64 + lane) * 8));
      }
#pragma unroll
      for (int fm = 0; fm < 4; ++fm)
#pragma unroll
        for (int fn = 0; fn < 4; ++fn)
          acc[fm][fn] = __builtin_amdgcn_mfma_f32_16x16x32_bf16(
              a[fm], b[fn], acc[fm][fn], 0, 0, 0);
    }
    __syncthreads();
  }

  // ---- epilogue: bias + relu + store (+ fused segment_sum for EDGE) ----
  // D mapping (m89-verified): col = lane&15, row = (lane>>4)*4 + i
  float bcol[4];
#pragma unroll
  for (int fn = 0; fn < 4; ++fn) bcol[fn] = bias[(wn * 4 + fn) * 16 + (lane & 15)];
#pragma unroll
  for (int fm = 0; fm < 4; ++fm) {
    int rb = row0 + wm * 64 + fm * 16 + ((lane >> 4) << 2);
#pragma unroll
    for (int i = 0; i < 4; ++i) {
      int gr = rb + i;
      if (gr < M) {
        int rcv = 0;
        if (EDGE) rcv = receivers[gr];
#pragma unroll
        for (int fn = 0; fn < 4; ++fn) {
          int col = (wn * 4 + fn) * 16 + (lane & 15);
          float v = fmaxf(acc[fm][fn][i] + bcol[fn], 0.0f);
          out[(size_t)gr * 256 + col] = v;
          if (EDGE) atomicAdd(agg + (size_t)rcv * 256 + col, v);
        }
      }
    }
  }
}

// column sums of an [rows,256] matrix, accumulated into out[256] (must be pre-zeroed)
__global__ void colsum(const float* __restrict__ in, float* __restrict__ out, int rows) {
  int c = threadIdx.x;
  float s = 0.f;
  for (int r = blockIdx.x; r < rows; r += gridDim.x) s += in[(size_t)r * 256 + c];
  atomicAdd(out + c, s);
}

// new_globals = relu([esum | nsum | globals] @ Wg + bg), all fp32
__global__ void global_mlp(const float* __restrict__ esum, const float* __restrict__ nsum,
                           const float* __restrict__ gl, const float* __restrict__ Wg,
                           const float* __restrict__ bg, float* __restrict__ out2) {
  int g = threadIdx.x;  // 128
  float acc = bg[g];
  for (int k = 0; k < 256; ++k) acc += esum[k] * Wg[(size_t)k * 128 + g];
  for (int k = 0; k < 256; ++k) acc += nsum[k] * Wg[(size_t)(256 + k) * 128 + g];
  for (int k = 0; k < 128; ++k) acc += gl[k] * Wg[(size_t)(512 + k) * 128 + g];
  out2[g] = fmaxf(acc, 0.f);
}

extern "C" void kernel_launch(void* const* d_in, const int* in_sizes, int n_in,
                              void* d_out, int out_size, void* d_ws, size_t ws_size,
                              hipStream_t stream) {
  const float* nodes = (const float*)d_in[0];
  const float* edges = (const float*)d_in[1];
  const float* gl = (const float*)d_in[2];
  const int* senders = (const int*)d_in[3];
  const int* receivers = (const int*)d_in[4];
  const float* We = (const float*)d_in[5];
  const float* be = (const float*)d_in[6];
  const float* Wn = (const float*)d_in[7];
  const float* bn = (const float*)d_in[8];
  const float* Wg = (const float*)d_in[9];
  const float* bg = (const float*)d_in[10];

  float* out0 = (float*)d_out;                    // new_edges [200000,256]
  float* out1 = out0 + (size_t)E_CNT * 256;       // new_nodes [50000,256]
  float* out2 = out1 + (size_t)N_CNT * 256;       // new_globals [128]

  char* ws = (char*)d_ws;
  float* agg = (float*)ws;                                 // 51,200,000 B
  float* esum = (float*)(ws + 51200000);                   // 1 KiB
  float* nsum = (float*)(ws + 51201024);                   // 1 KiB
  unsigned short* BpE = (unsigned short*)(ws + 51202048);  // 458,752 B
  unsigned short* BpN = (unsigned short*)(ws + 51660800);  // 327,680 B

  // zero agg + esum + nsum every call (we accumulate atomically)
  hipMemsetAsync(agg, 0, 51202048, stream);

  prep_w<<<112, 256, 0, stream>>>(We, BpE, 28);  // 896 = 28*32
  prep_w<<<80, 256, 0, stream>>>(Wn, BpN, 20);   // 640 = 20*32

  gemm_mlp<14, true><<<(E_CNT + 127) / 128, 512, 0, stream>>>(
      edges, nodes, gl, senders, receivers, BpE, be, out0, agg, E_CNT);

  colsum<<<256, 256, 0, stream>>>(agg, esum, N_CNT);  // colsum(agg) == colsum(new_edges)

  gemm_mlp<10, false><<<(N_CNT + 127) / 128, 512, 0, stream>>>(
      agg, nodes, gl, nullptr, nullptr, BpN, bn, out1, nullptr, N_CNT);

  colsum<<<256, 256, 0, stream>>>(out1, nsum, N_CNT);

  global_mlp<<<1, 128, 0, stream>>>(esum, nsum, gl, Wg, bg, out2);
}